// Round 15
// baseline (197.542 us; speedup 1.0000x reference)
//
#include <hip/hip_runtime.h>
#include <hip/hip_cooperative_groups.h>

namespace cg = cooperative_groups;

#define TPB 1024
#define GRID 256   // coop capacity on this stack is <=256 blocks (r2/r7). Never exceed.

// r14 post-mortem: VGPR_Count=64 -> RA targets 2 blocks/CU (8 waves/EU) for a
// 1024 block; we run 1 block/CU (coop), so 128 VGPR is legal. launch_bounds
// (TPB, 4) = min 4 waves/EU -> budget 128. With that, restore r13's full
// overlap: BOTH convs before the wait (acc 64 VGPR + feats 40 + temps < 128),
// serial path per layer = fold+finish+publish only.

typedef float f2 __attribute__((ext_vector_type(2)));
static __device__ __forceinline__ f2 spl(float s) { f2 r; r.x = s; r.y = s; return r; }

__global__ void __launch_bounds__(TPB, 4) risnet_kernel(
    const float* __restrict__ channel,
    const float* __restrict__ We1, const float* __restrict__ be1,
    const float* __restrict__ We,  const float* __restrict__ be,
    const float* __restrict__ Wo1, const float* __restrict__ bo1,
    const float* __restrict__ Wo,  const float* __restrict__ bo,
    const float* __restrict__ W8,  const float* __restrict__ b8,
    float* __restrict__ out, float* __restrict__ part, int* __restrict__ flags)
{
  const int tid   = threadIdx.x;
  const int lane  = tid & 63;
  const int wv    = tid >> 6;                 // 0..15
  const int p     = tid & 1;                  // user-half: owns users 2p, 2p+1
  const int B     = blockIdx.x;
  const int b     = (B & 7) * 8 + ((B >> 3) & 7);  // same B%8 (XCD) per b-group
  const int chunk = B >> 6;                   // 0..3
  const int n     = (chunk << 9) | (tid >> 1);// 0..2047

  __shared__ __align__(16) float biasE[16][4];
  __shared__ __align__(16) float biasO[16][4];
  __shared__ float red[64][64];                 // [row=wv*4+grp][conv*32+j*4+u]
  __shared__ float gv[64];                      // per-b means: ego-g 0..31, opp-g 32..63
  __shared__ float fin;

  if (tid == 0)
    __hip_atomic_store(&flags[B], 0, __ATOMIC_RELAXED, __HIP_MEMORY_SCOPE_AGENT);

  // per-thread channel slice, packed over the user pair: ch2[f] = {u=2p, u=2p+1}
  f2 ch2[4];
#pragma unroll
  for (int f = 0; f < 4; ++f) {
    ch2[f].x = channel[((b*4 + 2*p + 0)*4 + f)*2048 + n];
    ch2[f].y = channel[((b*4 + 2*p + 1)*4 + f)*2048 + n];
  }

  cg::grid_group grid = cg::this_grid();
  grid.sync();   // all flags zeroed before any block can set/wait (replay safety)

  f2 el2[8], ol2[8];

  // 3-level parity-preserving reduce: sums over the 8 same-parity lanes of
  // each 16-lane group. Writer lanes: (lane&15)<2; row = wv*4 + (lane>>4).
#define BFLY3(a0, a1) { \
  a0 += __shfl_xor(a0, 2, 64);  a1 += __shfl_xor(a1, 2, 64);  \
  a0 += __shfl_xor(a0, 4, 64);  a1 += __shfl_xor(a1, 4, 64);  \
  a0 += __shfl_xor(a0, 8, 64);  a1 += __shfl_xor(a1, 8, 64); }

#define RED_W(base_col, a0, a1) \
  if ((lane & 15) < 2) { \
    red[(wv<<2)|(lane>>4)][(base_col) + 2*(lane&1) + 0] = a0; \
    red[(wv<<2)|(lane>>4)][(base_col) + 2*(lane&1) + 1] = a1; }

#define PUBLISH(Lpar, Lval) { \
  __syncthreads(); \
  if (tid < 64) { \
    float s = 0.f; \
    _Pragma("unroll") for (int r = 0; r < 64; ++r) s += red[r][tid]; \
    __hip_atomic_store(&part[(((Lpar)*64 + b)*4 + chunk)*64 + tid], s, \
                       __ATOMIC_RELAXED, __HIP_MEMORY_SCOPE_AGENT); \
  } \
  if (tid == 0) \
    __hip_atomic_store(&flags[B], (Lval), __ATOMIC_RELEASE, __HIP_MEMORY_SCOPE_AGENT); }

#define WAIT_GATHER(Lpar, tgt) \
  if (tid < 64) { \
    const int gi = (B & 63) | ((lane & 3) << 6); \
    for (;;) { \
      int f = __hip_atomic_load(&flags[gi], __ATOMIC_ACQUIRE, __HIP_MEMORY_SCOPE_AGENT); \
      if (__all(f >= (tgt))) break; \
      __builtin_amdgcn_s_sleep(1); \
    } \
    float s = 0.f; \
    _Pragma("unroll") for (int k = 0; k < 4; ++k) \
      s += __hip_atomic_load(&part[(((Lpar)*64 + b)*4 + k)*64 + lane], \
                             __ATOMIC_RELAXED, __HIP_MEMORY_SCOPE_AGENT); \
    gv[lane] = s * (1.f/2048.f); \
  }

  // packed 20-col dot product (ch 0..3, el 4..11, ol 20..27)
#define DOT20(ACC, W0, W1, W2, W5, W6) { \
  f2 v = spl(0.f); \
  v = spl(W0.x)*ch2[0] + v; v = spl(W0.y)*ch2[1] + v; \
  v = spl(W0.z)*ch2[2] + v; v = spl(W0.w)*ch2[3] + v; \
  v = spl(W1.x)*el2[0] + v; v = spl(W1.y)*el2[1] + v; \
  v = spl(W1.z)*el2[2] + v; v = spl(W1.w)*el2[3] + v; \
  v = spl(W2.x)*el2[4] + v; v = spl(W2.y)*el2[5] + v; \
  v = spl(W2.z)*el2[6] + v; v = spl(W2.w)*el2[7] + v; \
  v = spl(W5.x)*ol2[0] + v; v = spl(W5.y)*ol2[1] + v; \
  v = spl(W5.z)*ol2[2] + v; v = spl(W5.w)*ol2[3] + v; \
  v = spl(W6.x)*ol2[4] + v; v = spl(W6.y)*ol2[5] + v; \
  v = spl(W6.z)*ol2[6] + v; v = spl(W6.w)*ol2[7] + v; \
  ACC = v; }

  // ---------------- layer 0 (Cin = 4, feats = ch) ----------------
  {
    f2 opl2[8];
#pragma unroll
    for (int h = 0; h < 16; ++h) {
      const float4 w = *(const float4*)(We1 + h*4);
      f2 a = spl(be1[h]);
      a = spl(w.x)*ch2[0] + a; a = spl(w.y)*ch2[1] + a;
      a = spl(w.z)*ch2[2] + a; a = spl(w.w)*ch2[3] + a;
      a.x = fmaxf(a.x, 0.f); a.y = fmaxf(a.y, 0.f);
      if (h < 8) el2[h] = a;
      else { float a0 = a.x, a1 = a.y; BFLY3(a0, a1); RED_W((h-8)*4, a0, a1); }
    }
#pragma unroll
    for (int h = 0; h < 16; ++h) {
      const float4 w = *(const float4*)(Wo1 + h*4);
      f2 a = spl(bo1[h]);
      a = spl(w.x)*ch2[0] + a; a = spl(w.y)*ch2[1] + a;
      a = spl(w.z)*ch2[2] + a; a = spl(w.w)*ch2[3] + a;
      a.x = fmaxf(a.x, 0.f); a.y = fmaxf(a.y, 0.f);
      if (h < 8) opl2[h] = a;
      else { float a0 = a.x, a1 = a.y; BFLY3(a0, a1); RED_W(32 + (h-8)*4, a0, a1); }
    }
#pragma unroll
    for (int j = 0; j < 8; ++j) {
      const float s2 = opl2[j].x + opl2[j].y;
      const float s4 = s2 + __shfl_xor(s2, 1, 64);
      ol2[j] = (spl(s4) - opl2[j]) * spl(1.f/3.f);
    }
  }
  PUBLISH(0, 1)

  // ---------------- layers 1..6 (Cin = 36) ----------------
  for (int L = 1; L < 7; ++L) {
    const float* __restrict__ wEl = We + (L-1)*576;   // wave-uniform -> s_loads
    const float* __restrict__ wOl = Wo + (L-1)*576;
    const int par_r = (L-1) & 1;
    const int par_w = L & 1;

    // --- phase 1: BOTH conv accumulators, no bias (overlaps the wait) ---
    f2 accE2[16], accO2[16];
#pragma unroll
    for (int h = 0; h < 16; ++h) {
      const float4* wr = (const float4*)(wEl + h*36);
      const float4 w0 = wr[0], w1 = wr[1], w2 = wr[2], w5 = wr[5], w6 = wr[6];
      DOT20(accE2[h], w0, w1, w2, w5, w6)
    }
#pragma unroll
    for (int h = 0; h < 16; ++h) {
      const float4* wr = (const float4*)(wOl + h*36);
      const float4 w0 = wr[0], w1 = wr[1], w2 = wr[2], w5 = wr[5], w6 = wr[6];
      DOT20(accO2[h], w0, w1, w2, w5, w6)
    }

    // --- phase 2: wait on own b-group + gather means (hidden under convs) ---
    WAIT_GATHER(par_r, L)
    __syncthreads();

    // --- phase 3: fold eg/og into per-(conv,u,h) bias ---
    if (tid < 128) {
      const int cv = tid >> 6;
      const int rr = tid & 63;
      const int u  = rr & 3;
      const int h  = rr >> 2;
      const float* W = cv ? wOl : wEl;
      float bias = cv ? bo[(L-1)*16 + h] : be[(L-1)*16 + h];
#pragma unroll
      for (int j = 0; j < 8; ++j) {
        const float eg = gv[j*4 + u];
        const float so = gv[32+j*4+0] + gv[32+j*4+1] + gv[32+j*4+2] + gv[32+j*4+3];
        const float og = (so - gv[32 + j*4 + u]) * (1.f/3.f);
        bias += W[h*36 + 12 + j] * eg + W[h*36 + 28 + j] * og;
      }
      if (cv) biasO[h][u] = bias; else biasE[h][u] = bias;
    }
    __syncthreads();

    // --- phase 4: add bias, relu, reduce h>=8, LOO, commit ---
    f2 opl2[8];
#pragma unroll
    for (int h = 0; h < 16; ++h) {
      f2 a = accE2[h] + *(const f2*)&biasE[h][2*p];
      a.x = fmaxf(a.x, 0.f); a.y = fmaxf(a.y, 0.f);
      if (h < 8) el2[h] = a;
      else { float a0 = a.x, a1 = a.y; BFLY3(a0, a1); RED_W((h-8)*4, a0, a1); }
    }
#pragma unroll
    for (int h = 0; h < 16; ++h) {
      f2 a = accO2[h] + *(const f2*)&biasO[h][2*p];
      a.x = fmaxf(a.x, 0.f); a.y = fmaxf(a.y, 0.f);
      if (h < 8) opl2[h] = a;
      else { float a0 = a.x, a1 = a.y; BFLY3(a0, a1); RED_W(32 + (h-8)*4, a0, a1); }
    }
#pragma unroll
    for (int j = 0; j < 8; ++j) {
      const float s2 = opl2[j].x + opl2[j].y;
      const float s4 = s2 + __shfl_xor(s2, 1, 64);
      ol2[j] = (spl(s4) - opl2[j]) * spl(1.f/3.f);
    }
    PUBLISH(par_w, L + 1)
  }

  // ---------------- final 1x1 conv + mean over users ----------------
  WAIT_GATHER(0, 7)   // layer 6 wrote parity 0
  __syncthreads();
  if (tid == 0) {
    float s = b8[0];
#pragma unroll
    for (int j = 0; j < 8; ++j) {
      const float so = gv[32+j*4+0] + gv[32+j*4+1] + gv[32+j*4+2] + gv[32+j*4+3];
#pragma unroll
      for (int u = 0; u < 4; ++u) {
        const float eg = gv[j*4 + u];
        const float og = (so - gv[32 + j*4 + u]) * (1.f/3.f);
        s += 0.25f * (W8[12 + j] * eg + W8[28 + j] * og);
      }
    }
    fin = s;
  }
  __syncthreads();
  f2 v = spl(0.f);
#pragma unroll
  for (int c = 0; c < 4; ++c) v = spl(W8[c]) * ch2[c] + v;
#pragma unroll
  for (int j = 0; j < 8; ++j) {
    v = spl(W8[4 + j]) * el2[j] + v;
    v = spl(W8[20 + j]) * ol2[j] + v;
  }
  float t = v.x + v.y;
  t += __shfl_xor(t, 1, 64);   // sum over all 4 users
  if (p == 0)
    out[b*2048 + n] = (fin + 0.25f * t) * 3.14159265358979f;
}

extern "C" void kernel_launch(void* const* d_in, const int* in_sizes, int n_in,
                              void* d_out, int out_size, void* d_ws, size_t ws_size,
                              hipStream_t stream) {
  const float* channel = (const float*)d_in[0];
  const float* We1 = (const float*)d_in[1];
  const float* be1 = (const float*)d_in[2];
  const float* We  = (const float*)d_in[3];
  const float* be  = (const float*)d_in[4];
  const float* Wo1 = (const float*)d_in[5];
  const float* bo1 = (const float*)d_in[6];
  const float* Wo  = (const float*)d_in[7];
  const float* bo  = (const float*)d_in[8];
  const float* W8  = (const float*)d_in[9];
  const float* b8  = (const float*)d_in[10];
  float* out  = (float*)d_out;
  float* part = (float*)d_ws;                       // 2*64*4*64 floats = 131072 B
  int*   flags = (int*)((char*)d_ws + 131072);      // 256 ints

  void* args[] = { (void*)&channel, (void*)&We1, (void*)&be1, (void*)&We, (void*)&be,
                   (void*)&Wo1, (void*)&bo1, (void*)&Wo, (void*)&bo,
                   (void*)&W8, (void*)&b8, (void*)&out, (void*)&part, (void*)&flags };
  hipLaunchCooperativeKernel((void*)risnet_kernel, dim3(GRID), dim3(TPB), args, 0, stream);
}

// Round 16
// 157.305 us; speedup vs baseline: 1.2558x; 1.2558x over previous
//
#include <hip/hip_runtime.h>
#include <hip/hip_cooperative_groups.h>

namespace cg = cooperative_groups;

#define TPB 1024
#define GRID 256   // coop capacity on this stack is <=256 blocks (r2/r7). Never exceed.

// r15 post-mortem: __launch_bounds__(1024,4) was a no-op (VGPR stayed 64,
// full-overlap spilled 8MB). Pattern: launch_bounds NEVER raises the RA
// budget; target tracks 2 blocks/CU. This round: NO launch_bounds; pin
// occupancy via native attrs flat_work_group_size(1024,1024) +
// waves_per_eu(4,4) -> budget 128 VGPR. Body = r14 (split conv, best 156us).
// Check: VGPR_Count. If still 64, abandon the budget lever.

typedef float f2 __attribute__((ext_vector_type(2)));
static __device__ __forceinline__ f2 spl(float s) { f2 r; r.x = s; r.y = s; return r; }

__global__ void
__attribute__((amdgpu_flat_work_group_size(1024, 1024)))
__attribute__((amdgpu_waves_per_eu(4, 4)))
risnet_kernel(
    const float* __restrict__ channel,
    const float* __restrict__ We1, const float* __restrict__ be1,
    const float* __restrict__ We,  const float* __restrict__ be,
    const float* __restrict__ Wo1, const float* __restrict__ bo1,
    const float* __restrict__ Wo,  const float* __restrict__ bo,
    const float* __restrict__ W8,  const float* __restrict__ b8,
    float* __restrict__ out, float* __restrict__ part, int* __restrict__ flags)
{
  const int tid   = threadIdx.x;
  const int lane  = tid & 63;
  const int wv    = tid >> 6;                 // 0..15
  const int p     = tid & 1;                  // user-half: owns users 2p, 2p+1
  const int B     = blockIdx.x;
  const int b     = (B & 7) * 8 + ((B >> 3) & 7);  // same B%8 (XCD) per b-group
  const int chunk = B >> 6;                   // 0..3
  const int n     = (chunk << 9) | (tid >> 1);// 0..2047

  __shared__ __align__(16) float biasE[16][4];
  __shared__ __align__(16) float biasO[16][4];
  __shared__ float red[64][64];                 // [row=wv*4+grp][conv*32+j*4+u]
  __shared__ float gv[64];                      // per-b means: ego-g 0..31, opp-g 32..63
  __shared__ float fin;

  if (tid == 0)
    __hip_atomic_store(&flags[B], 0, __ATOMIC_RELAXED, __HIP_MEMORY_SCOPE_AGENT);

  // per-thread channel slice, packed over the user pair: ch2[f] = {u=2p, u=2p+1}
  f2 ch2[4];
#pragma unroll
  for (int f = 0; f < 4; ++f) {
    ch2[f].x = channel[((b*4 + 2*p + 0)*4 + f)*2048 + n];
    ch2[f].y = channel[((b*4 + 2*p + 1)*4 + f)*2048 + n];
  }

  cg::grid_group grid = cg::this_grid();
  grid.sync();   // all flags zeroed before any block can set/wait (replay safety)

  f2 el2[8], ol2[8];

  // 3-level parity-preserving reduce: sums over the 8 same-parity lanes of
  // each 16-lane group. Writer lanes: (lane&15)<2; row = wv*4 + (lane>>4).
#define BFLY3(a0, a1) { \
  a0 += __shfl_xor(a0, 2, 64);  a1 += __shfl_xor(a1, 2, 64);  \
  a0 += __shfl_xor(a0, 4, 64);  a1 += __shfl_xor(a1, 4, 64);  \
  a0 += __shfl_xor(a0, 8, 64);  a1 += __shfl_xor(a1, 8, 64); }

#define RED_W(base_col, a0, a1) \
  if ((lane & 15) < 2) { \
    red[(wv<<2)|(lane>>4)][(base_col) + 2*(lane&1) + 0] = a0; \
    red[(wv<<2)|(lane>>4)][(base_col) + 2*(lane&1) + 1] = a1; }

#define PUBLISH(Lpar, Lval) { \
  __syncthreads(); \
  if (tid < 64) { \
    float s = 0.f; \
    _Pragma("unroll") for (int r = 0; r < 64; ++r) s += red[r][tid]; \
    __hip_atomic_store(&part[(((Lpar)*64 + b)*4 + chunk)*64 + tid], s, \
                       __ATOMIC_RELAXED, __HIP_MEMORY_SCOPE_AGENT); \
  } \
  if (tid == 0) \
    __hip_atomic_store(&flags[B], (Lval), __ATOMIC_RELEASE, __HIP_MEMORY_SCOPE_AGENT); }

#define WAIT_GATHER(Lpar, tgt) \
  if (tid < 64) { \
    const int gi = (B & 63) | ((lane & 3) << 6); \
    for (;;) { \
      int f = __hip_atomic_load(&flags[gi], __ATOMIC_ACQUIRE, __HIP_MEMORY_SCOPE_AGENT); \
      if (__all(f >= (tgt))) break; \
      __builtin_amdgcn_s_sleep(1); \
    } \
    float s = 0.f; \
    _Pragma("unroll") for (int k = 0; k < 4; ++k) \
      s += __hip_atomic_load(&part[(((Lpar)*64 + b)*4 + k)*64 + lane], \
                             __ATOMIC_RELAXED, __HIP_MEMORY_SCOPE_AGENT); \
    gv[lane] = s * (1.f/2048.f); \
  }

  // packed 20-col dot product (ch 0..3, el 4..11, ol 20..27), BINIT = bias or 0
#define DOT20B(ACC, W0, W1, W2, W5, W6, BINIT) { \
  f2 v = (BINIT); \
  v = spl(W0.x)*ch2[0] + v; v = spl(W0.y)*ch2[1] + v; \
  v = spl(W0.z)*ch2[2] + v; v = spl(W0.w)*ch2[3] + v; \
  v = spl(W1.x)*el2[0] + v; v = spl(W1.y)*el2[1] + v; \
  v = spl(W1.z)*el2[2] + v; v = spl(W1.w)*el2[3] + v; \
  v = spl(W2.x)*el2[4] + v; v = spl(W2.y)*el2[5] + v; \
  v = spl(W2.z)*el2[6] + v; v = spl(W2.w)*el2[7] + v; \
  v = spl(W5.x)*ol2[0] + v; v = spl(W5.y)*ol2[1] + v; \
  v = spl(W5.z)*ol2[2] + v; v = spl(W5.w)*ol2[3] + v; \
  v = spl(W6.x)*ol2[4] + v; v = spl(W6.y)*ol2[5] + v; \
  v = spl(W6.z)*ol2[6] + v; v = spl(W6.w)*ol2[7] + v; \
  ACC = v; }

  // ---------------- layer 0 (Cin = 4, feats = ch) ----------------
  {
    f2 opl2[8];
#pragma unroll
    for (int h = 0; h < 16; ++h) {
      const float4 w = *(const float4*)(We1 + h*4);
      f2 a = spl(be1[h]);
      a = spl(w.x)*ch2[0] + a; a = spl(w.y)*ch2[1] + a;
      a = spl(w.z)*ch2[2] + a; a = spl(w.w)*ch2[3] + a;
      a.x = fmaxf(a.x, 0.f); a.y = fmaxf(a.y, 0.f);
      if (h < 8) el2[h] = a;
      else { float a0 = a.x, a1 = a.y; BFLY3(a0, a1); RED_W((h-8)*4, a0, a1); }
    }
#pragma unroll
    for (int h = 0; h < 16; ++h) {
      const float4 w = *(const float4*)(Wo1 + h*4);
      f2 a = spl(bo1[h]);
      a = spl(w.x)*ch2[0] + a; a = spl(w.y)*ch2[1] + a;
      a = spl(w.z)*ch2[2] + a; a = spl(w.w)*ch2[3] + a;
      a.x = fmaxf(a.x, 0.f); a.y = fmaxf(a.y, 0.f);
      if (h < 8) opl2[h] = a;
      else { float a0 = a.x, a1 = a.y; BFLY3(a0, a1); RED_W(32 + (h-8)*4, a0, a1); }
    }
#pragma unroll
    for (int j = 0; j < 8; ++j) {
      const float s2 = opl2[j].x + opl2[j].y;
      const float s4 = s2 + __shfl_xor(s2, 1, 64);
      ol2[j] = (spl(s4) - opl2[j]) * spl(1.f/3.f);
    }
  }
  PUBLISH(0, 1)

  // ---------------- layers 1..6 (Cin = 36) ----------------
  for (int L = 1; L < 7; ++L) {
    const float* __restrict__ wEl = We + (L-1)*576;   // wave-uniform -> s_loads
    const float* __restrict__ wOl = Wo + (L-1)*576;
    const int par_r = (L-1) & 1;
    const int par_w = L & 1;

    // --- phase 1: EGO conv only, no bias (16 f2 cross the barrier) ---
    f2 accE2[16];
#pragma unroll
    for (int h = 0; h < 16; ++h) {
      const float4* wr = (const float4*)(wEl + h*36);
      const float4 w0 = wr[0], w1 = wr[1], w2 = wr[2], w5 = wr[5], w6 = wr[6];
      DOT20B(accE2[h], w0, w1, w2, w5, w6, spl(0.f))
    }

    // --- phase 2: wait on own b-group + gather means (hidden under ego) ---
    WAIT_GATHER(par_r, L)
    __syncthreads();

    // --- phase 3: fold eg/og into per-(conv,u,h) bias ---
    if (tid < 128) {
      const int cv = tid >> 6;
      const int rr = tid & 63;
      const int u  = rr & 3;
      const int h  = rr >> 2;
      const float* W = cv ? wOl : wEl;
      float bias = cv ? bo[(L-1)*16 + h] : be[(L-1)*16 + h];
#pragma unroll
      for (int j = 0; j < 8; ++j) {
        const float eg = gv[j*4 + u];
        const float so = gv[32+j*4+0] + gv[32+j*4+1] + gv[32+j*4+2] + gv[32+j*4+3];
        const float og = (so - gv[32 + j*4 + u]) * (1.f/3.f);
        bias += W[h*36 + 12 + j] * eg + W[h*36 + 28 + j] * og;
      }
      if (cv) biasO[h][u] = bias; else biasE[h][u] = bias;
    }
    __syncthreads();

    // --- phase 4a: finish ego (bias, relu, reduce h>=8); el_new in eln2 ---
    f2 eln2[8];
#pragma unroll
    for (int h = 0; h < 16; ++h) {
      f2 a = accE2[h] + *(const f2*)&biasE[h][2*p];
      a.x = fmaxf(a.x, 0.f); a.y = fmaxf(a.y, 0.f);
      if (h < 8) eln2[h] = a;
      else { float a0 = a.x, a1 = a.y; BFLY3(a0, a1); RED_W((h-8)*4, a0, a1); }
    }
    // --- phase 4b: OPP conv born with bias init (uses OLD el2/ol2) ---
    f2 opl2[8];
#pragma unroll
    for (int h = 0; h < 16; ++h) {
      const float4* wr = (const float4*)(wOl + h*36);
      const float4 w0 = wr[0], w1 = wr[1], w2 = wr[2], w5 = wr[5], w6 = wr[6];
      f2 a;
      DOT20B(a, w0, w1, w2, w5, w6, *(const f2*)&biasO[h][2*p])
      a.x = fmaxf(a.x, 0.f); a.y = fmaxf(a.y, 0.f);
      if (h < 8) opl2[h] = a;
      else { float a0 = a.x, a1 = a.y; BFLY3(a0, a1); RED_W(32 + (h-8)*4, a0, a1); }
    }
    // --- LOO + commit new features ---
#pragma unroll
    for (int j = 0; j < 8; ++j) {
      const float s2 = opl2[j].x + opl2[j].y;
      const float s4 = s2 + __shfl_xor(s2, 1, 64);
      ol2[j] = (spl(s4) - opl2[j]) * spl(1.f/3.f);
      el2[j] = eln2[j];
    }
    PUBLISH(par_w, L + 1)
  }

  // ---------------- final 1x1 conv + mean over users ----------------
  WAIT_GATHER(0, 7)   // layer 6 wrote parity 0
  __syncthreads();
  if (tid == 0) {
    float s = b8[0];
#pragma unroll
    for (int j = 0; j < 8; ++j) {
      const float so = gv[32+j*4+0] + gv[32+j*4+1] + gv[32+j*4+2] + gv[32+j*4+3];
#pragma unroll
      for (int u = 0; u < 4; ++u) {
        const float eg = gv[j*4 + u];
        const float og = (so - gv[32 + j*4 + u]) * (1.f/3.f);
        s += 0.25f * (W8[12 + j] * eg + W8[28 + j] * og);
      }
    }
    fin = s;
  }
  __syncthreads();
  f2 v = spl(0.f);
#pragma unroll
  for (int c = 0; c < 4; ++c) v = spl(W8[c]) * ch2[c] + v;
#pragma unroll
  for (int j = 0; j < 8; ++j) {
    v = spl(W8[4 + j]) * el2[j] + v;
    v = spl(W8[20 + j]) * ol2[j] + v;
  }
  float t = v.x + v.y;
  t += __shfl_xor(t, 1, 64);   // sum over all 4 users
  if (p == 0)
    out[b*2048 + n] = (fin + 0.25f * t) * 3.14159265358979f;
}

extern "C" void kernel_launch(void* const* d_in, const int* in_sizes, int n_in,
                              void* d_out, int out_size, void* d_ws, size_t ws_size,
                              hipStream_t stream) {
  const float* channel = (const float*)d_in[0];
  const float* We1 = (const float*)d_in[1];
  const float* be1 = (const float*)d_in[2];
  const float* We  = (const float*)d_in[3];
  const float* be  = (const float*)d_in[4];
  const float* Wo1 = (const float*)d_in[5];
  const float* bo1 = (const float*)d_in[6];
  const float* Wo  = (const float*)d_in[7];
  const float* bo  = (const float*)d_in[8];
  const float* W8  = (const float*)d_in[9];
  const float* b8  = (const float*)d_in[10];
  float* out  = (float*)d_out;
  float* part = (float*)d_ws;                       // 2*64*4*64 floats = 131072 B
  int*   flags = (int*)((char*)d_ws + 131072);      // 256 ints

  void* args[] = { (void*)&channel, (void*)&We1, (void*)&be1, (void*)&We, (void*)&be,
                   (void*)&Wo1, (void*)&bo1, (void*)&Wo, (void*)&bo,
                   (void*)&W8, (void*)&b8, (void*)&out, (void*)&part, (void*)&flags };
  hipLaunchCooperativeKernel((void*)risnet_kernel, dim3(GRID), dim3(TPB), args, 0, stream);
}

// Round 17
// 146.357 us; speedup vs baseline: 1.3497x; 1.0748x over previous
//
#include <hip/hip_runtime.h>
#include <hip/hip_cooperative_groups.h>

namespace cg = cooperative_groups;

#define TPB 1024
#define GRID 256   // coop capacity on this stack is <=256 blocks (r2/r7). Never exceed.

// r16 post-mortem: VGPR hard-capped at 64 for TPB=1024 (all attrs ignored).
// Stall ~100us = protocol (3 barriers/layer + idle fold + late publish).
// r17: (1) wave15 fuses wait+gather+fold (r11 pattern; bias parity-double-
// buffered to fix the barrier-removal race) -> 2 barriers/layer; (2) publish-
// early: h>=8 are stats-only (LOO uses h<8), so finish-hi + opp-hi first,
// publish, then lo halves + LOO in the flag-propagation shadow.

typedef float f2 __attribute__((ext_vector_type(2)));
static __device__ __forceinline__ f2 spl(float s) { f2 r; r.x = s; r.y = s; return r; }

__global__ void risnet_kernel(
    const float* __restrict__ channel,
    const float* __restrict__ We1, const float* __restrict__ be1,
    const float* __restrict__ We,  const float* __restrict__ be,
    const float* __restrict__ Wo1, const float* __restrict__ bo1,
    const float* __restrict__ Wo,  const float* __restrict__ bo,
    const float* __restrict__ W8,  const float* __restrict__ b8,
    float* __restrict__ out, float* __restrict__ part, int* __restrict__ flags)
{
  const int tid   = threadIdx.x;
  const int lane  = tid & 63;
  const int wv    = tid >> 6;                 // 0..15
  const int p     = tid & 1;                  // user-half: owns users 2p, 2p+1
  const int B     = blockIdx.x;
  const int b     = (B & 7) * 8 + ((B >> 3) & 7);  // same B%8 (XCD) per b-group
  const int chunk = B >> 6;                   // 0..3
  const int n     = (chunk << 9) | (tid >> 1);// 0..2047

  __shared__ __align__(16) float biasE[2][16][4];  // [L&1][h][u] parity dbuf
  __shared__ __align__(16) float biasO[2][16][4];
  __shared__ float red[64][64];                 // [row=wv*4+grp][conv*32+j*4+u]
  __shared__ float gv[64];                      // per-b means: ego-g 0..31, opp-g 32..63
  __shared__ float fin;

  if (tid == 0)
    __hip_atomic_store(&flags[B], 0, __ATOMIC_RELAXED, __HIP_MEMORY_SCOPE_AGENT);

  // per-thread channel slice, packed over the user pair: ch2[f] = {u=2p, u=2p+1}
  f2 ch2[4];
#pragma unroll
  for (int f = 0; f < 4; ++f) {
    ch2[f].x = channel[((b*4 + 2*p + 0)*4 + f)*2048 + n];
    ch2[f].y = channel[((b*4 + 2*p + 1)*4 + f)*2048 + n];
  }

  cg::grid_group grid = cg::this_grid();
  grid.sync();   // all flags zeroed before any block can set/wait (replay safety)

  f2 el2[8], ol2[8];

#define BFLY3(a0, a1) { \
  a0 += __shfl_xor(a0, 2, 64);  a1 += __shfl_xor(a1, 2, 64);  \
  a0 += __shfl_xor(a0, 4, 64);  a1 += __shfl_xor(a1, 4, 64);  \
  a0 += __shfl_xor(a0, 8, 64);  a1 += __shfl_xor(a1, 8, 64); }

#define RED_W(base_col, a0, a1) \
  if ((lane & 15) < 2) { \
    red[(wv<<2)|(lane>>4)][(base_col) + 2*(lane&1) + 0] = a0; \
    red[(wv<<2)|(lane>>4)][(base_col) + 2*(lane&1) + 1] = a1; }

#define PUBLISH(Lpar, Lval) { \
  __syncthreads(); \
  if (tid < 64) { \
    float s = 0.f; \
    _Pragma("unroll") for (int r = 0; r < 64; ++r) s += red[r][tid]; \
    __hip_atomic_store(&part[(((Lpar)*64 + b)*4 + chunk)*64 + tid], s, \
                       __ATOMIC_RELAXED, __HIP_MEMORY_SCOPE_AGENT); \
  } \
  if (tid == 0) \
    __hip_atomic_store(&flags[B], (Lval), __ATOMIC_RELEASE, __HIP_MEMORY_SCOPE_AGENT); }

  // packed 20-col dot product (ch 0..3, el 4..11, ol 20..27), BINIT = bias or 0
#define DOT20B(ACC, W0, W1, W2, W5, W6, BINIT) { \
  f2 v = (BINIT); \
  v = spl(W0.x)*ch2[0] + v; v = spl(W0.y)*ch2[1] + v; \
  v = spl(W0.z)*ch2[2] + v; v = spl(W0.w)*ch2[3] + v; \
  v = spl(W1.x)*el2[0] + v; v = spl(W1.y)*el2[1] + v; \
  v = spl(W1.z)*el2[2] + v; v = spl(W1.w)*el2[3] + v; \
  v = spl(W2.x)*el2[4] + v; v = spl(W2.y)*el2[5] + v; \
  v = spl(W2.z)*el2[6] + v; v = spl(W2.w)*el2[7] + v; \
  v = spl(W5.x)*ol2[0] + v; v = spl(W5.y)*ol2[1] + v; \
  v = spl(W5.z)*ol2[2] + v; v = spl(W5.w)*ol2[3] + v; \
  v = spl(W6.x)*ol2[4] + v; v = spl(W6.y)*ol2[5] + v; \
  v = spl(W6.z)*ol2[6] + v; v = spl(W6.w)*ol2[7] + v; \
  ACC = v; }

  // ---------------- layer 0 (Cin = 4, feats = ch) ----------------
  {
    f2 opl2[8];
#pragma unroll
    for (int h = 0; h < 16; ++h) {
      const float4 w = *(const float4*)(We1 + h*4);
      f2 a = spl(be1[h]);
      a = spl(w.x)*ch2[0] + a; a = spl(w.y)*ch2[1] + a;
      a = spl(w.z)*ch2[2] + a; a = spl(w.w)*ch2[3] + a;
      a.x = fmaxf(a.x, 0.f); a.y = fmaxf(a.y, 0.f);
      if (h < 8) el2[h] = a;
      else { float a0 = a.x, a1 = a.y; BFLY3(a0, a1); RED_W((h-8)*4, a0, a1); }
    }
#pragma unroll
    for (int h = 0; h < 16; ++h) {
      const float4 w = *(const float4*)(Wo1 + h*4);
      f2 a = spl(bo1[h]);
      a = spl(w.x)*ch2[0] + a; a = spl(w.y)*ch2[1] + a;
      a = spl(w.z)*ch2[2] + a; a = spl(w.w)*ch2[3] + a;
      a.x = fmaxf(a.x, 0.f); a.y = fmaxf(a.y, 0.f);
      if (h < 8) opl2[h] = a;
      else { float a0 = a.x, a1 = a.y; BFLY3(a0, a1); RED_W(32 + (h-8)*4, a0, a1); }
    }
#pragma unroll
    for (int j = 0; j < 8; ++j) {
      const float s2 = opl2[j].x + opl2[j].y;
      const float s4 = s2 + __shfl_xor(s2, 1, 64);
      ol2[j] = (spl(s4) - opl2[j]) * spl(1.f/3.f);
    }
  }
  PUBLISH(0, 1)

  // ---------------- layers 1..6 (Cin = 36) ----------------
  for (int L = 1; L < 7; ++L) {
    const float* __restrict__ wEl = We + (L-1)*576;   // wave-uniform -> s_loads
    const float* __restrict__ wOl = Wo + (L-1)*576;
    const int par_r = (L-1) & 1;
    const int par_w = L & 1;
    const int bb    = L & 1;       // bias parity buffer

    // --- phase 1: EGO conv, no bias (16 f2 cross the fold barrier) ---
    f2 accE2[16];
#pragma unroll
    for (int h = 0; h < 16; ++h) {
      const float4* wr = (const float4*)(wEl + h*36);
      const float4 w0 = wr[0], w1 = wr[1], w2 = wr[2], w5 = wr[5], w6 = wr[6];
      DOT20B(accE2[h], w0, w1, w2, w5, w6, spl(0.f))
    }

    // --- wave15: spin on b-group, gather means, fold BOTH bias sets ---
    if (wv == 15) {
      const int gi = (B & 63) | ((lane & 3) << 6);
      for (;;) {
        int f = __hip_atomic_load(&flags[gi], __ATOMIC_ACQUIRE, __HIP_MEMORY_SCOPE_AGENT);
        if (__all(f >= L)) break;
        __builtin_amdgcn_s_sleep(1);
      }
      float s = 0.f;
#pragma unroll
      for (int k = 0; k < 4; ++k)
        s += __hip_atomic_load(&part[((par_r*64 + b)*4 + k)*64 + lane],
                               __ATOMIC_RELAXED, __HIP_MEMORY_SCOPE_AGENT);
      gv[lane] = s * (1.f/2048.f);
      // same-wave LDS RAW (r11-verified pattern): lane owns (u,h), folds both convs
      const int u = lane & 3;
      const int h = lane >> 2;
      float bE = be[(L-1)*16 + h];
      float bO = bo[(L-1)*16 + h];
#pragma unroll
      for (int j = 0; j < 8; ++j) {
        const float eg = gv[j*4 + u];
        const float so = gv[32+j*4+0] + gv[32+j*4+1] + gv[32+j*4+2] + gv[32+j*4+3];
        const float og = (so - gv[32 + j*4 + u]) * (1.f/3.f);
        bE += wEl[h*36 + 12 + j] * eg + wEl[h*36 + 28 + j] * og;
        bO += wOl[h*36 + 12 + j] * eg + wOl[h*36 + 28 + j] * og;
      }
      biasE[bb][h][u] = bE;
      biasO[bb][h][u] = bO;
    }
    __syncthreads();   // barrier 1: biases ready

    // --- finish ego HI (stats-only rows) + opp HI conv -> publish early ---
#pragma unroll
    for (int h = 8; h < 16; ++h) {
      f2 a = accE2[h] + *(const f2*)&biasE[bb][h][2*p];
      float a0 = fmaxf(a.x, 0.f), a1 = fmaxf(a.y, 0.f);
      BFLY3(a0, a1); RED_W((h-8)*4, a0, a1);
    }
#pragma unroll
    for (int h = 8; h < 16; ++h) {
      const float4* wr = (const float4*)(wOl + h*36);
      const float4 w0 = wr[0], w1 = wr[1], w2 = wr[2], w5 = wr[5], w6 = wr[6];
      f2 a;
      DOT20B(a, w0, w1, w2, w5, w6, *(const f2*)&biasO[bb][h][2*p])
      float a0 = fmaxf(a.x, 0.f), a1 = fmaxf(a.y, 0.f);
      BFLY3(a0, a1); RED_W(32 + (h-8)*4, a0, a1);
    }
    PUBLISH(par_w, L + 1)   // barrier 2 + wave0 publish + flag (early)

    // --- lo halves in the flag-propagation shadow ---
    f2 eln2[8];
#pragma unroll
    for (int h = 0; h < 8; ++h) {
      f2 a = accE2[h] + *(const f2*)&biasE[bb][h][2*p];
      a.x = fmaxf(a.x, 0.f); a.y = fmaxf(a.y, 0.f);
      eln2[h] = a;
    }
    f2 opl2[8];
#pragma unroll
    for (int h = 0; h < 8; ++h) {
      const float4* wr = (const float4*)(wOl + h*36);
      const float4 w0 = wr[0], w1 = wr[1], w2 = wr[2], w5 = wr[5], w6 = wr[6];
      f2 a;
      DOT20B(a, w0, w1, w2, w5, w6, *(const f2*)&biasO[bb][h][2*p])
      a.x = fmaxf(a.x, 0.f); a.y = fmaxf(a.y, 0.f);
      opl2[h] = a;
    }
#pragma unroll
    for (int j = 0; j < 8; ++j) {
      const float s2 = opl2[j].x + opl2[j].y;
      const float s4 = s2 + __shfl_xor(s2, 1, 64);
      ol2[j] = (spl(s4) - opl2[j]) * spl(1.f/3.f);
      el2[j] = eln2[j];
    }
  }

  // ---------------- final 1x1 conv + mean over users ----------------
  if (wv == 0) {   // layer 6 wrote parity 0, flag 7
    const int gi = (B & 63) | ((lane & 3) << 6);
    for (;;) {
      int f = __hip_atomic_load(&flags[gi], __ATOMIC_ACQUIRE, __HIP_MEMORY_SCOPE_AGENT);
      if (__all(f >= 7)) break;
      __builtin_amdgcn_s_sleep(1);
    }
    float s = 0.f;
#pragma unroll
    for (int k = 0; k < 4; ++k)
      s += __hip_atomic_load(&part[((0*64 + b)*4 + k)*64 + lane],
                             __ATOMIC_RELAXED, __HIP_MEMORY_SCOPE_AGENT);
    gv[lane] = s * (1.f/2048.f);
    if (lane == 0) {
      float sf = b8[0];
#pragma unroll
      for (int j = 0; j < 8; ++j) {
        const float so = gv[32+j*4+0] + gv[32+j*4+1] + gv[32+j*4+2] + gv[32+j*4+3];
#pragma unroll
        for (int u = 0; u < 4; ++u) {
          const float eg = gv[j*4 + u];
          const float og = (so - gv[32 + j*4 + u]) * (1.f/3.f);
          sf += 0.25f * (W8[12 + j] * eg + W8[28 + j] * og);
        }
      }
      fin = sf;
    }
  }
  __syncthreads();
  f2 v = spl(0.f);
#pragma unroll
  for (int c = 0; c < 4; ++c) v = spl(W8[c]) * ch2[c] + v;
#pragma unroll
  for (int j = 0; j < 8; ++j) {
    v = spl(W8[4 + j]) * el2[j] + v;
    v = spl(W8[20 + j]) * ol2[j] + v;
  }
  float t = v.x + v.y;
  t += __shfl_xor(t, 1, 64);   // sum over all 4 users
  if (p == 0)
    out[b*2048 + n] = (fin + 0.25f * t) * 3.14159265358979f;
}

extern "C" void kernel_launch(void* const* d_in, const int* in_sizes, int n_in,
                              void* d_out, int out_size, void* d_ws, size_t ws_size,
                              hipStream_t stream) {
  const float* channel = (const float*)d_in[0];
  const float* We1 = (const float*)d_in[1];
  const float* be1 = (const float*)d_in[2];
  const float* We  = (const float*)d_in[3];
  const float* be  = (const float*)d_in[4];
  const float* Wo1 = (const float*)d_in[5];
  const float* bo1 = (const float*)d_in[6];
  const float* Wo  = (const float*)d_in[7];
  const float* bo  = (const float*)d_in[8];
  const float* W8  = (const float*)d_in[9];
  const float* b8  = (const float*)d_in[10];
  float* out  = (float*)d_out;
  float* part = (float*)d_ws;                       // 2*64*4*64 floats = 131072 B
  int*   flags = (int*)((char*)d_ws + 131072);      // 256 ints

  void* args[] = { (void*)&channel, (void*)&We1, (void*)&be1, (void*)&We, (void*)&be,
                   (void*)&Wo1, (void*)&bo1, (void*)&Wo, (void*)&bo,
                   (void*)&W8, (void*)&b8, (void*)&out, (void*)&part, (void*)&flags };
  hipLaunchCooperativeKernel((void*)risnet_kernel, dim3(GRID), dim3(TPB), args, 0, stream);
}

// Round 18
// 141.571 us; speedup vs baseline: 1.3954x; 1.0338x over previous
//
#include <hip/hip_runtime.h>
#include <hip/hip_cooperative_groups.h>

namespace cg = cooperative_groups;

#define TPB 1024
#define GRID 256   // coop capacity on this stack is <=256 blocks (r2/r7). Never exceed.

// r17 post-mortem: stall ~99us invariant across structures -> the handoff
// itself. Theory: acquire-agent load PER POLL ITERATION emits a cache
// invalidate every ~64cy (slow detection + evicts weights for the other 15
// waves). r18: poll RELAXED, single acquire FENCE after the loop (standard
// fence-based acquire); publish sum uses 4 accumulators to cut the 64-deep
// dependent LDS add chain.

typedef float f2 __attribute__((ext_vector_type(2)));
static __device__ __forceinline__ f2 spl(float s) { f2 r; r.x = s; r.y = s; return r; }

__global__ void risnet_kernel(
    const float* __restrict__ channel,
    const float* __restrict__ We1, const float* __restrict__ be1,
    const float* __restrict__ We,  const float* __restrict__ be,
    const float* __restrict__ Wo1, const float* __restrict__ bo1,
    const float* __restrict__ Wo,  const float* __restrict__ bo,
    const float* __restrict__ W8,  const float* __restrict__ b8,
    float* __restrict__ out, float* __restrict__ part, int* __restrict__ flags)
{
  const int tid   = threadIdx.x;
  const int lane  = tid & 63;
  const int wv    = tid >> 6;                 // 0..15
  const int p     = tid & 1;                  // user-half: owns users 2p, 2p+1
  const int B     = blockIdx.x;
  const int b     = (B & 7) * 8 + ((B >> 3) & 7);  // same B%8 (XCD) per b-group
  const int chunk = B >> 6;                   // 0..3
  const int n     = (chunk << 9) | (tid >> 1);// 0..2047

  __shared__ __align__(16) float biasE[2][16][4];  // [L&1][h][u] parity dbuf
  __shared__ __align__(16) float biasO[2][16][4];
  __shared__ float red[64][64];                 // [row=wv*4+grp][conv*32+j*4+u]
  __shared__ float gv[64];                      // per-b means: ego-g 0..31, opp-g 32..63
  __shared__ float fin;

  if (tid == 0)
    __hip_atomic_store(&flags[B], 0, __ATOMIC_RELAXED, __HIP_MEMORY_SCOPE_AGENT);

  // per-thread channel slice, packed over the user pair: ch2[f] = {u=2p, u=2p+1}
  f2 ch2[4];
#pragma unroll
  for (int f = 0; f < 4; ++f) {
    ch2[f].x = channel[((b*4 + 2*p + 0)*4 + f)*2048 + n];
    ch2[f].y = channel[((b*4 + 2*p + 1)*4 + f)*2048 + n];
  }

  cg::grid_group grid = cg::this_grid();
  grid.sync();   // all flags zeroed before any block can set/wait (replay safety)

  f2 el2[8], ol2[8];

#define BFLY3(a0, a1) { \
  a0 += __shfl_xor(a0, 2, 64);  a1 += __shfl_xor(a1, 2, 64);  \
  a0 += __shfl_xor(a0, 4, 64);  a1 += __shfl_xor(a1, 4, 64);  \
  a0 += __shfl_xor(a0, 8, 64);  a1 += __shfl_xor(a1, 8, 64); }

#define RED_W(base_col, a0, a1) \
  if ((lane & 15) < 2) { \
    red[(wv<<2)|(lane>>4)][(base_col) + 2*(lane&1) + 0] = a0; \
    red[(wv<<2)|(lane>>4)][(base_col) + 2*(lane&1) + 1] = a1; }

#define PUBLISH(Lpar, Lval) { \
  __syncthreads(); \
  if (tid < 64) { \
    float s0 = 0.f, s1 = 0.f, s2 = 0.f, s3 = 0.f; \
    _Pragma("unroll") for (int r = 0; r < 64; r += 4) { \
      s0 += red[r+0][tid]; s1 += red[r+1][tid]; \
      s2 += red[r+2][tid]; s3 += red[r+3][tid]; \
    } \
    __hip_atomic_store(&part[(((Lpar)*64 + b)*4 + chunk)*64 + tid], \
                       (s0+s1)+(s2+s3), \
                       __ATOMIC_RELAXED, __HIP_MEMORY_SCOPE_AGENT); \
  } \
  if (tid == 0) \
    __hip_atomic_store(&flags[B], (Lval), __ATOMIC_RELEASE, __HIP_MEMORY_SCOPE_AGENT); }

  // relaxed spin (no per-poll invalidate) + ONE acquire fence after
#define SPIN_RELAXED(tgt) { \
  const int gi = (B & 63) | ((lane & 3) << 6); \
  for (;;) { \
    int f = __hip_atomic_load(&flags[gi], __ATOMIC_RELAXED, __HIP_MEMORY_SCOPE_AGENT); \
    if (__all(f >= (tgt))) break; \
    __builtin_amdgcn_s_sleep(1); \
  } \
  __builtin_amdgcn_fence(__ATOMIC_ACQUIRE, "agent"); }

  // packed 20-col dot product (ch 0..3, el 4..11, ol 20..27), BINIT = bias or 0
#define DOT20B(ACC, W0, W1, W2, W5, W6, BINIT) { \
  f2 v = (BINIT); \
  v = spl(W0.x)*ch2[0] + v; v = spl(W0.y)*ch2[1] + v; \
  v = spl(W0.z)*ch2[2] + v; v = spl(W0.w)*ch2[3] + v; \
  v = spl(W1.x)*el2[0] + v; v = spl(W1.y)*el2[1] + v; \
  v = spl(W1.z)*el2[2] + v; v = spl(W1.w)*el2[3] + v; \
  v = spl(W2.x)*el2[4] + v; v = spl(W2.y)*el2[5] + v; \
  v = spl(W2.z)*el2[6] + v; v = spl(W2.w)*el2[7] + v; \
  v = spl(W5.x)*ol2[0] + v; v = spl(W5.y)*ol2[1] + v; \
  v = spl(W5.z)*ol2[2] + v; v = spl(W5.w)*ol2[3] + v; \
  v = spl(W6.x)*ol2[4] + v; v = spl(W6.y)*ol2[5] + v; \
  v = spl(W6.z)*ol2[6] + v; v = spl(W6.w)*ol2[7] + v; \
  ACC = v; }

  // ---------------- layer 0 (Cin = 4, feats = ch) ----------------
  {
    f2 opl2[8];
#pragma unroll
    for (int h = 0; h < 16; ++h) {
      const float4 w = *(const float4*)(We1 + h*4);
      f2 a = spl(be1[h]);
      a = spl(w.x)*ch2[0] + a; a = spl(w.y)*ch2[1] + a;
      a = spl(w.z)*ch2[2] + a; a = spl(w.w)*ch2[3] + a;
      a.x = fmaxf(a.x, 0.f); a.y = fmaxf(a.y, 0.f);
      if (h < 8) el2[h] = a;
      else { float a0 = a.x, a1 = a.y; BFLY3(a0, a1); RED_W((h-8)*4, a0, a1); }
    }
#pragma unroll
    for (int h = 0; h < 16; ++h) {
      const float4 w = *(const float4*)(Wo1 + h*4);
      f2 a = spl(bo1[h]);
      a = spl(w.x)*ch2[0] + a; a = spl(w.y)*ch2[1] + a;
      a = spl(w.z)*ch2[2] + a; a = spl(w.w)*ch2[3] + a;
      a.x = fmaxf(a.x, 0.f); a.y = fmaxf(a.y, 0.f);
      if (h < 8) opl2[h] = a;
      else { float a0 = a.x, a1 = a.y; BFLY3(a0, a1); RED_W(32 + (h-8)*4, a0, a1); }
    }
#pragma unroll
    for (int j = 0; j < 8; ++j) {
      const float s2 = opl2[j].x + opl2[j].y;
      const float s4 = s2 + __shfl_xor(s2, 1, 64);
      ol2[j] = (spl(s4) - opl2[j]) * spl(1.f/3.f);
    }
  }
  PUBLISH(0, 1)

  // ---------------- layers 1..6 (Cin = 36) ----------------
  for (int L = 1; L < 7; ++L) {
    const float* __restrict__ wEl = We + (L-1)*576;   // wave-uniform -> s_loads
    const float* __restrict__ wOl = Wo + (L-1)*576;
    const int par_r = (L-1) & 1;
    const int par_w = L & 1;
    const int bb    = L & 1;       // bias parity buffer

    // --- phase 1: EGO conv, no bias (16 f2 cross the fold barrier) ---
    f2 accE2[16];
#pragma unroll
    for (int h = 0; h < 16; ++h) {
      const float4* wr = (const float4*)(wEl + h*36);
      const float4 w0 = wr[0], w1 = wr[1], w2 = wr[2], w5 = wr[5], w6 = wr[6];
      DOT20B(accE2[h], w0, w1, w2, w5, w6, spl(0.f))
    }

    // --- wave15: spin on b-group, gather means, fold BOTH bias sets ---
    if (wv == 15) {
      SPIN_RELAXED(L)
      float s = 0.f;
#pragma unroll
      for (int k = 0; k < 4; ++k)
        s += __hip_atomic_load(&part[((par_r*64 + b)*4 + k)*64 + lane],
                               __ATOMIC_RELAXED, __HIP_MEMORY_SCOPE_AGENT);
      gv[lane] = s * (1.f/2048.f);
      // same-wave LDS RAW (r11-verified pattern): lane owns (u,h), folds both convs
      const int u = lane & 3;
      const int h = lane >> 2;
      float bE = be[(L-1)*16 + h];
      float bO = bo[(L-1)*16 + h];
#pragma unroll
      for (int j = 0; j < 8; ++j) {
        const float eg = gv[j*4 + u];
        const float so = gv[32+j*4+0] + gv[32+j*4+1] + gv[32+j*4+2] + gv[32+j*4+3];
        const float og = (so - gv[32 + j*4 + u]) * (1.f/3.f);
        bE += wEl[h*36 + 12 + j] * eg + wEl[h*36 + 28 + j] * og;
        bO += wOl[h*36 + 12 + j] * eg + wOl[h*36 + 28 + j] * og;
      }
      biasE[bb][h][u] = bE;
      biasO[bb][h][u] = bO;
    }
    __syncthreads();   // barrier 1: biases ready

    // --- finish ego HI (stats-only rows) + opp HI conv -> publish early ---
#pragma unroll
    for (int h = 8; h < 16; ++h) {
      f2 a = accE2[h] + *(const f2*)&biasE[bb][h][2*p];
      float a0 = fmaxf(a.x, 0.f), a1 = fmaxf(a.y, 0.f);
      BFLY3(a0, a1); RED_W((h-8)*4, a0, a1);
    }
#pragma unroll
    for (int h = 8; h < 16; ++h) {
      const float4* wr = (const float4*)(wOl + h*36);
      const float4 w0 = wr[0], w1 = wr[1], w2 = wr[2], w5 = wr[5], w6 = wr[6];
      f2 a;
      DOT20B(a, w0, w1, w2, w5, w6, *(const f2*)&biasO[bb][h][2*p])
      float a0 = fmaxf(a.x, 0.f), a1 = fmaxf(a.y, 0.f);
      BFLY3(a0, a1); RED_W(32 + (h-8)*4, a0, a1);
    }
    PUBLISH(par_w, L + 1)   // barrier 2 + wave0 publish + flag (early)

    // --- lo halves in the flag-propagation shadow ---
    f2 eln2[8];
#pragma unroll
    for (int h = 0; h < 8; ++h) {
      f2 a = accE2[h] + *(const f2*)&biasE[bb][h][2*p];
      a.x = fmaxf(a.x, 0.f); a.y = fmaxf(a.y, 0.f);
      eln2[h] = a;
    }
    f2 opl2[8];
#pragma unroll
    for (int h = 0; h < 8; ++h) {
      const float4* wr = (const float4*)(wOl + h*36);
      const float4 w0 = wr[0], w1 = wr[1], w2 = wr[2], w5 = wr[5], w6 = wr[6];
      f2 a;
      DOT20B(a, w0, w1, w2, w5, w6, *(const f2*)&biasO[bb][h][2*p])
      a.x = fmaxf(a.x, 0.f); a.y = fmaxf(a.y, 0.f);
      opl2[h] = a;
    }
#pragma unroll
    for (int j = 0; j < 8; ++j) {
      const float s2 = opl2[j].x + opl2[j].y;
      const float s4 = s2 + __shfl_xor(s2, 1, 64);
      ol2[j] = (spl(s4) - opl2[j]) * spl(1.f/3.f);
      el2[j] = eln2[j];
    }
  }

  // ---------------- final 1x1 conv + mean over users ----------------
  if (wv == 0) {   // layer 6 wrote parity 0, flag 7
    SPIN_RELAXED(7)
    float s = 0.f;
#pragma unroll
    for (int k = 0; k < 4; ++k)
      s += __hip_atomic_load(&part[((0*64 + b)*4 + k)*64 + lane],
                             __ATOMIC_RELAXED, __HIP_MEMORY_SCOPE_AGENT);
    gv[lane] = s * (1.f/2048.f);
    if (lane == 0) {
      float sf = b8[0];
#pragma unroll
      for (int j = 0; j < 8; ++j) {
        const float so = gv[32+j*4+0] + gv[32+j*4+1] + gv[32+j*4+2] + gv[32+j*4+3];
#pragma unroll
        for (int u = 0; u < 4; ++u) {
          const float eg = gv[j*4 + u];
          const float og = (so - gv[32 + j*4 + u]) * (1.f/3.f);
          sf += 0.25f * (W8[12 + j] * eg + W8[28 + j] * og);
        }
      }
      fin = sf;
    }
  }
  __syncthreads();
  f2 v = spl(0.f);
#pragma unroll
  for (int c = 0; c < 4; ++c) v = spl(W8[c]) * ch2[c] + v;
#pragma unroll
  for (int j = 0; j < 8; ++j) {
    v = spl(W8[4 + j]) * el2[j] + v;
    v = spl(W8[20 + j]) * ol2[j] + v;
  }
  float t = v.x + v.y;
  t += __shfl_xor(t, 1, 64);   // sum over all 4 users
  if (p == 0)
    out[b*2048 + n] = (fin + 0.25f * t) * 3.14159265358979f;
}

extern "C" void kernel_launch(void* const* d_in, const int* in_sizes, int n_in,
                              void* d_out, int out_size, void* d_ws, size_t ws_size,
                              hipStream_t stream) {
  const float* channel = (const float*)d_in[0];
  const float* We1 = (const float*)d_in[1];
  const float* be1 = (const float*)d_in[2];
  const float* We  = (const float*)d_in[3];
  const float* be  = (const float*)d_in[4];
  const float* Wo1 = (const float*)d_in[5];
  const float* bo1 = (const float*)d_in[6];
  const float* Wo  = (const float*)d_in[7];
  const float* bo  = (const float*)d_in[8];
  const float* W8  = (const float*)d_in[9];
  const float* b8  = (const float*)d_in[10];
  float* out  = (float*)d_out;
  float* part = (float*)d_ws;                       // 2*64*4*64 floats = 131072 B
  int*   flags = (int*)((char*)d_ws + 131072);      // 256 ints

  void* args[] = { (void*)&channel, (void*)&We1, (void*)&be1, (void*)&We, (void*)&be,
                   (void*)&Wo1, (void*)&bo1, (void*)&Wo, (void*)&bo,
                   (void*)&W8, (void*)&b8, (void*)&out, (void*)&part, (void*)&flags };
  hipLaunchCooperativeKernel((void*)risnet_kernel, dim3(GRID), dim3(TPB), args, 0, stream);
}